// Round 1
// baseline (1111.147 us; speedup 1.0000x reference)
//
#include <hip/hip_runtime.h>
#include <cstdint>
#include <cstddef>

#define BATCH 16

static constexpr int NN0 = 32768, NN1 = 8192, NN2 = 2048, NN3 = 512, NN4 = 128;

// ---------------- weight transpose: W (CO, K) -> Wt (K, CO) ----------------
__global__ __launch_bounds__(256) void transpose_w(const float* __restrict__ W,
                                                   float* __restrict__ Wt,
                                                   int CO, int K) {
    int i = blockIdx.x * 256 + threadIdx.x;
    if (i < CO * K) {
        int c = i / K, k = i - c * K;
        Wt[k * CO + c] = W[i];
    }
}

// ---------------- fused gather + conv + bias (+ELU) ----------------
// x: (B, N, CIN), idx: (N, 9), Wt: (K=9*CIN, COUT), out: (B, N, COUT)
template<int CIN, int COUT, int VPB, bool ELU>
__global__ __launch_bounds__(256) void conv_kernel(const float* __restrict__ x,
                                                   const int* __restrict__ idx,
                                                   const float* __restrict__ Wt,
                                                   const float* __restrict__ bias,
                                                   float* __restrict__ out,
                                                   int N) {
    constexpr int K   = CIN * 9;
    constexpr int GS  = K + 4;          // padded LDS row stride: 16B-aligned, %32 != 0
    constexpr int TPV = COUT / 4;       // threads per vertex (each thread does 4 out ch)
    static_assert(VPB * TPV == 256, "block mapping");
    constexpr int KCC = (K < 144) ? K : 144;
    static_assert(K % KCC == 0, "chunking");

    __shared__ float g[VPB][GS];
    __shared__ float Wc[KCC][COUT];
    __shared__ int   nbr[VPB][9];

    const int b  = blockIdx.y;
    const int v0 = blockIdx.x * VPB;
    const float* __restrict__ xb = x + (size_t)b * N * CIN;

    for (int t = threadIdx.x; t < VPB * 9; t += 256)
        nbr[t / 9][t % 9] = idx[v0 * 9 + t];
    __syncthreads();

    if constexpr ((CIN & 3) == 0) {
        constexpr int QPV = 9 * CIN / 4;       // float4 quads per vertex row
        for (int q = threadIdx.x; q < VPB * QPV; q += 256) {
            const int v  = q / QPV, r = q - v * QPV;
            const int s  = r / (CIN / 4), cq = r - s * (CIN / 4);
            const float4 t = *reinterpret_cast<const float4*>(
                xb + (size_t)nbr[v][s] * CIN + cq * 4);
            *reinterpret_cast<float4*>(&g[v][s * CIN + cq * 4]) = t;
        }
    } else {
        constexpr int EPV = 9 * CIN;
        for (int e = threadIdx.x; e < VPB * EPV; e += 256) {
            const int v = e / EPV, r = e - v * EPV;
            const int s = r / CIN, c = r - s * CIN;
            g[v][r] = xb[(size_t)nbr[v][s] * CIN + c];
        }
    }

    const int v  = threadIdx.x / TPV;
    const int cb = (threadIdx.x % TPV) * 4;
    float a0 = 0.f, a1 = 0.f, a2 = 0.f, a3 = 0.f;

    for (int kc = 0; kc < K; kc += KCC) {
        __syncthreads();   // protects g (first iter) and Wc (later iters)
        for (int q = threadIdx.x; q < KCC * (COUT / 4); q += 256) {
            const int kk = q / (COUT / 4), cq = q - kk * (COUT / 4);
            *reinterpret_cast<float4*>(&Wc[kk][cq * 4]) =
                *reinterpret_cast<const float4*>(Wt + (size_t)(kc + kk) * COUT + cq * 4);
        }
        __syncthreads();
        #pragma unroll 4
        for (int kk = 0; kk < KCC; ++kk) {
            const float  gv = g[v][kc + kk];
            const float4 w  = *reinterpret_cast<const float4*>(&Wc[kk][cb]);
            a0 += gv * w.x; a1 += gv * w.y; a2 += gv * w.z; a3 += gv * w.w;
        }
    }

    const float4 bv = *reinterpret_cast<const float4*>(bias + cb);
    a0 += bv.x; a1 += bv.y; a2 += bv.z; a3 += bv.w;
    if constexpr (ELU) {
        a0 = a0 > 0.f ? a0 : expm1f(a0);
        a1 = a1 > 0.f ? a1 : expm1f(a1);
        a2 = a2 > 0.f ? a2 : expm1f(a2);
        a3 = a3 > 0.f ? a3 : expm1f(a3);
    }
    float4 o; o.x = a0; o.y = a1; o.z = a2; o.w = a3;
    *reinterpret_cast<float4*>(out + ((size_t)b * N + v0 + v) * COUT + cb) = o;
}

// ---------------- final conv, COUT=3, CIN=32, no ELU ----------------
__global__ __launch_bounds__(256) void out_conv_kernel(const float* __restrict__ x,
                                                       const int* __restrict__ idx,
                                                       const float* __restrict__ Wt, // (288,3)
                                                       const float* __restrict__ bias,
                                                       float* __restrict__ out,
                                                       int N) {
    __shared__ float Wl[288 * 3];
    for (int t = threadIdx.x; t < 288 * 3; t += 256) Wl[t] = Wt[t];
    __syncthreads();
    const int b = blockIdx.y;
    const int v = blockIdx.x * 256 + threadIdx.x;
    const float* __restrict__ xb = x + (size_t)b * N * 32;
    float a0 = bias[0], a1 = bias[1], a2 = bias[2];
    #pragma unroll
    for (int s = 0; s < 9; ++s) {
        const int n = idx[v * 9 + s];
        const float* xs = xb + (size_t)n * 32;
        #pragma unroll
        for (int cq = 0; cq < 8; ++cq) {
            const float4 xv = *reinterpret_cast<const float4*>(xs + cq * 4);
            const int k = (s * 32 + cq * 4) * 3;
            a0 += xv.x * Wl[k + 0] + xv.y * Wl[k + 3] + xv.z * Wl[k + 6] + xv.w * Wl[k + 9];
            a1 += xv.x * Wl[k + 1] + xv.y * Wl[k + 4] + xv.z * Wl[k + 7] + xv.w * Wl[k + 10];
            a2 += xv.x * Wl[k + 2] + xv.y * Wl[k + 5] + xv.z * Wl[k + 8] + xv.w * Wl[k + 11];
        }
    }
    float* o = out + ((size_t)b * N + v) * 3;
    o[0] = a0; o[1] = a1; o[2] = a2;
}

// ---------------- pool: out[b,r,:] = sum_{j<3} val[3r+j] * x[b, col[3r+j], :] ----------------
template<int C>
__global__ __launch_bounds__(256) void pool_kernel(const float* __restrict__ x,
                                                   const int* __restrict__ col,
                                                   const float* __restrict__ val,
                                                   float* __restrict__ out,
                                                   int Nout, int Nin) {
    constexpr int CQ = C / 4;
    const int q = blockIdx.x * 256 + threadIdx.x;
    if (q >= BATCH * Nout * CQ) return;
    const int cq = q % CQ;
    const int r  = (q / CQ) % Nout;
    const int b  = q / (CQ * Nout);
    float ax = 0.f, ay = 0.f, az = 0.f, aw = 0.f;
    #pragma unroll
    for (int j = 0; j < 3; ++j) {
        const int   c0 = col[3 * r + j];
        const float vl = val[3 * r + j];
        const float4 xv = *reinterpret_cast<const float4*>(
            x + ((size_t)b * Nin + c0) * C + cq * 4);
        ax += vl * xv.x; ay += vl * xv.y; az += vl * xv.z; aw += vl * xv.w;
    }
    float4 o; o.x = ax; o.y = ay; o.z = az; o.w = aw;
    *reinterpret_cast<float4*>(out + ((size_t)b * Nout + r) * C + cq * 4) = o;
}

// ---------------- encoder FC: z = sigmoid(h @ fcW^T + fcb), h (16,8192) ----------------
__global__ __launch_bounds__(256) void fc_enc_kernel(const float* __restrict__ h,
                                                     const float* __restrict__ W,   // (256, 8192)
                                                     const float* __restrict__ bias,
                                                     float* __restrict__ z,
                                                     float* __restrict__ out_z,
                                                     float* __restrict__ out_mu) {
    const int l = blockIdx.x;                 // latent index
    const float* __restrict__ wr = W + (size_t)l * 8192;
    float acc[BATCH];
    #pragma unroll
    for (int b = 0; b < BATCH; ++b) acc[b] = 0.f;
    for (int k = threadIdx.x * 4; k < 8192; k += 256 * 4) {
        const float4 w4 = *reinterpret_cast<const float4*>(wr + k);
        #pragma unroll
        for (int b = 0; b < BATCH; ++b) {
            const float4 h4 = *reinterpret_cast<const float4*>(h + (size_t)b * 8192 + k);
            acc[b] += w4.x * h4.x + w4.y * h4.y + w4.z * h4.z + w4.w * h4.w;
        }
    }
    __shared__ float red[BATCH][4];
    const int wid = threadIdx.x >> 6, lane = threadIdx.x & 63;
    #pragma unroll
    for (int b = 0; b < BATCH; ++b) {
        float v = acc[b];
        for (int off = 32; off; off >>= 1) v += __shfl_down(v, off);
        if (lane == 0) red[b][wid] = v;
    }
    __syncthreads();
    if (threadIdx.x < BATCH) {
        const int b = threadIdx.x;
        float s = red[b][0] + red[b][1] + red[b][2] + red[b][3] + bias[l];
        s = 1.f / (1.f + expf(-s));
        z[b * 256 + l]      = s;
        out_z[b * 256 + l]  = s;
        out_mu[b * 256 + l] = s;
    }
}

// ---------------- decoder FC: h = z @ dfcW^T + dfcb -> (16, 8192) ----------------
__global__ __launch_bounds__(256) void fc_dec_kernel(const float* __restrict__ z,   // (16,256)
                                                     const float* __restrict__ W,   // (8192,256)
                                                     const float* __restrict__ bias,
                                                     float* __restrict__ out) {     // (16,8192)
    __shared__ float zl[BATCH * 256];
    for (int t = threadIdx.x; t < BATCH * 256; t += 256) zl[t] = z[t];
    __syncthreads();
    const int m = blockIdx.x * 256 + threadIdx.x;   // 8192 threads
    const float* __restrict__ wr = W + (size_t)m * 256;
    float acc[BATCH];
    #pragma unroll
    for (int b = 0; b < BATCH; ++b) acc[b] = 0.f;
    for (int l = 0; l < 256; l += 4) {
        const float4 w4 = *reinterpret_cast<const float4*>(wr + l);
        #pragma unroll
        for (int b = 0; b < BATCH; ++b) {
            acc[b] += w4.x * zl[b * 256 + l]     + w4.y * zl[b * 256 + l + 1]
                    + w4.z * zl[b * 256 + l + 2] + w4.w * zl[b * 256 + l + 3];
        }
    }
    const float bm = bias[m];
    #pragma unroll
    for (int b = 0; b < BATCH; ++b) out[(size_t)b * 8192 + m] = acc[b] + bm;
}

// ---------------- host-side orchestration ----------------
extern "C" void kernel_launch(void* const* d_in, const int* in_sizes, int n_in,
                              void* d_out, int out_size, void* d_ws, size_t ws_size,
                              hipStream_t stream) {
    (void)in_sizes; (void)n_in; (void)out_size; (void)ws_size;

    const float* x = (const float*)d_in[0];
    const int* si[4] = {(const int*)d_in[1], (const int*)d_in[2],
                        (const int*)d_in[3], (const int*)d_in[4]};
    const int*   dcol[4]; const float* dval[4];
    const int*   ucol[4]; const float* uval[4];
    for (int i = 0; i < 4; ++i) {
        dcol[i] = (const int*)  d_in[5 + 6 * i + 1];
        dval[i] = (const float*)d_in[5 + 6 * i + 2];
        ucol[i] = (const int*)  d_in[5 + 6 * i + 4];
        uval[i] = (const float*)d_in[5 + 6 * i + 5];
    }
    const float *enW[4], *enb[4], *deW[4], *deb[4];
    for (int i = 0; i < 4; ++i) {
        enW[i] = (const float*)d_in[29 + 2 * i];
        enb[i] = (const float*)d_in[30 + 2 * i];
        deW[i] = (const float*)d_in[41 + 2 * i];
        deb[i] = (const float*)d_in[42 + 2 * i];
    }
    const float* fcW  = (const float*)d_in[37];
    const float* fcb  = (const float*)d_in[38];
    const float* dfcW = (const float*)d_in[39];
    const float* dfcb = (const float*)d_in[40];
    const float* outW = (const float*)d_in[49];
    const float* outb = (const float*)d_in[50];

    // workspace layout (floats): A | Bb | z | transposed weights  (~135 MB total)
    float* ws = (float*)d_ws;
    float* A  = ws;
    float* Bb = A  + (size_t)BATCH * NN0 * 32;
    float* z  = Bb + (size_t)BATCH * NN0 * 32;
    float* wt_en0 = z + BATCH * 256;
    float* wt_en1 = wt_en0 + 27  * 32;
    float* wt_en2 = wt_en1 + 288 * 32;
    float* wt_en3 = wt_en2 + 288 * 32;
    float* wt_de0 = wt_en3 + 288 * 64;
    float* wt_de1 = wt_de0 + 576 * 64;
    float* wt_de2 = wt_de1 + 576 * 32;
    float* wt_de3 = wt_de2 + 288 * 32;
    float* wt_out = wt_de3 + 288 * 32;

    float* out   = (float*)d_out;                     // (16, 32768, 3)
    float* out_z = out + (size_t)BATCH * NN0 * 3;     // (16, 256)
    float* out_mu = out_z + BATCH * 256;              // (16, 256)

    auto T = [&](const float* W, float* Wt, int CO, int K) {
        int n = CO * K;
        transpose_w<<<(n + 255) / 256, 256, 0, stream>>>(W, Wt, CO, K);
    };
    T(enW[0], wt_en0, 32, 27);
    T(enW[1], wt_en1, 32, 288);
    T(enW[2], wt_en2, 32, 288);
    T(enW[3], wt_en3, 64, 288);
    T(deW[0], wt_de0, 64, 576);
    T(deW[1], wt_de1, 32, 576);
    T(deW[2], wt_de2, 32, 288);
    T(deW[3], wt_de3, 32, 288);
    T(outW,   wt_out, 3,  288);

    // ---------------- encoder ----------------
    conv_kernel<3, 32, 32, true><<<dim3(NN0 / 32, BATCH), 256, 0, stream>>>(
        x, si[0], wt_en0, enb[0], A, NN0);
    pool_kernel<32><<<(BATCH * NN1 * 8) / 256, 256, 0, stream>>>(A, dcol[0], dval[0], Bb, NN1, NN0);
    conv_kernel<32, 32, 32, true><<<dim3(NN1 / 32, BATCH), 256, 0, stream>>>(
        Bb, si[1], wt_en1, enb[1], A, NN1);
    pool_kernel<32><<<(BATCH * NN2 * 8) / 256, 256, 0, stream>>>(A, dcol[1], dval[1], Bb, NN2, NN1);
    conv_kernel<32, 32, 32, true><<<dim3(NN2 / 32, BATCH), 256, 0, stream>>>(
        Bb, si[2], wt_en2, enb[2], A, NN2);
    pool_kernel<32><<<(BATCH * NN3 * 8) / 256, 256, 0, stream>>>(A, dcol[2], dval[2], Bb, NN3, NN2);
    conv_kernel<32, 64, 16, true><<<dim3(NN3 / 16, BATCH), 256, 0, stream>>>(
        Bb, si[3], wt_en3, enb[3], A, NN3);
    pool_kernel<64><<<(BATCH * NN4 * 16) / 256, 256, 0, stream>>>(A, dcol[3], dval[3], Bb, NN4, NN3);

    // ---------------- latent ----------------
    fc_enc_kernel<<<256, 256, 0, stream>>>(Bb, fcW, fcb, z, out_z, out_mu);
    fc_dec_kernel<<<32, 256, 0, stream>>>(z, dfcW, dfcb, A);

    // ---------------- decoder ----------------
    pool_kernel<64><<<(BATCH * NN3 * 16) / 256, 256, 0, stream>>>(A, ucol[3], uval[3], Bb, NN3, NN4);
    conv_kernel<64, 64, 16, true><<<dim3(NN3 / 16, BATCH), 256, 0, stream>>>(
        Bb, si[3], wt_de0, deb[0], A, NN3);
    pool_kernel<64><<<(BATCH * NN2 * 16) / 256, 256, 0, stream>>>(A, ucol[2], uval[2], Bb, NN2, NN3);
    conv_kernel<64, 32, 32, true><<<dim3(NN2 / 32, BATCH), 256, 0, stream>>>(
        Bb, si[2], wt_de1, deb[1], A, NN2);
    pool_kernel<32><<<(BATCH * NN1 * 8) / 256, 256, 0, stream>>>(A, ucol[1], uval[1], Bb, NN1, NN2);
    conv_kernel<32, 32, 32, true><<<dim3(NN1 / 32, BATCH), 256, 0, stream>>>(
        Bb, si[1], wt_de2, deb[2], A, NN1);
    pool_kernel<32><<<(BATCH * NN0 * 8) / 256, 256, 0, stream>>>(A, ucol[0], uval[0], Bb, NN0, NN1);
    conv_kernel<32, 32, 32, true><<<dim3(NN0 / 32, BATCH), 256, 0, stream>>>(
        Bb, si[0], wt_de3, deb[3], A, NN0);

    // ---------------- output head ----------------
    out_conv_kernel<<<dim3(NN0 / 256, BATCH), 256, 0, stream>>>(
        A, si[0], wt_out, outb, out, NN0);
}

// Round 2
// 965.061 us; speedup vs baseline: 1.1514x; 1.1514x over previous
//
#include <hip/hip_runtime.h>
#include <cstdint>
#include <cstddef>

#define BATCH 16

static constexpr int NN0 = 32768, NN1 = 8192, NN2 = 2048, NN3 = 512, NN4 = 128;

// ---------------- weight transpose: W (CO, K) -> Wt (K, CO) ----------------
__global__ __launch_bounds__(256) void transpose_w(const float* __restrict__ W,
                                                   float* __restrict__ Wt,
                                                   int CO, int K) {
    int i = blockIdx.x * 256 + threadIdx.x;
    if (i < CO * K) {
        int c = i / K, k = i - c * K;
        Wt[k * CO + c] = W[i];
    }
}

// ---------------- register-tiled fused gather+conv+bias(+ELU), CIN%4==0 ----------------
// Per-neighbor k-chunking (chunk = CIN). Thread computes VT vertices x 4 channels.
// x: (B,N,CIN), idx: (N,9), Wt: (9*CIN, COUT), out: (B,N,COUT)
template<int CIN, int COUT, int VPB, bool ELU>
__global__ __launch_bounds__(256) void conv_tiled(const float* __restrict__ x,
                                                  const int* __restrict__ idx,
                                                  const float* __restrict__ Wt,
                                                  const float* __restrict__ bias,
                                                  float* __restrict__ out,
                                                  int N) {
    constexpr int NQ  = COUT / 4;       // channel quads (threads per vertex-group slice)
    constexpr int VGN = 256 / NQ;       // vertex groups per block
    constexpr int VT  = VPB / VGN;      // vertices per thread
    static_assert(VPB % VGN == 0 && VT >= 1, "tile mapping");
    constexpr int GS  = CIN + 4;        // row stride: 16B aligned, ==4 mod 32 -> staggered quads
    constexpr int CQ  = CIN / 4;

    __shared__ float g[VPB][GS];
    __shared__ float Wc[CIN][COUT];
    __shared__ int   nbr[VPB][9];

    const int b  = blockIdx.y;
    const int v0 = blockIdx.x * VPB;
    const float* __restrict__ xb = x + (size_t)b * N * CIN;

    for (int t = threadIdx.x; t < VPB * 9; t += 256)
        nbr[t / 9][t % 9] = idx[v0 * 9 + t];

    const int qc = threadIdx.x % NQ;        // channel quad
    const int vg = threadIdx.x / NQ;        // vertex group base

    float4 acc[VT];
    #pragma unroll
    for (int i = 0; i < VT; ++i) acc[i] = make_float4(0.f, 0.f, 0.f, 0.f);

    for (int s = 0; s < 9; ++s) {
        __syncthreads();   // iter0: nbr ready; later: previous compute done reading g/Wc
        // ---- stage gathered x rows for neighbor s (coalesced 128B/256B rows) ----
        constexpr int GSLOTS = VPB * CQ;
        #pragma unroll
        for (int p = 0; p < (GSLOTS + 255) / 256; ++p) {
            const int slot = p * 256 + threadIdx.x;
            if (GSLOTS % 256 == 0 || slot < GSLOTS) {
                const int v = slot / CQ, q = slot - v * CQ;
                const float4 t4 = *reinterpret_cast<const float4*>(
                    xb + (size_t)nbr[v][s] * CIN + q * 4);
                *reinterpret_cast<float4*>(&g[v][q * 4]) = t4;
            }
        }
        // ---- stage weight chunk rows s*CIN .. s*CIN+CIN-1 ----
        constexpr int WSLOTS = CIN * NQ;
        #pragma unroll
        for (int p = 0; p < (WSLOTS + 255) / 256; ++p) {
            const int slot = p * 256 + threadIdx.x;
            if (WSLOTS % 256 == 0 || slot < WSLOTS) {
                const int r = slot / NQ, q = slot - r * NQ;
                *reinterpret_cast<float4*>(&Wc[r][q * 4]) =
                    *reinterpret_cast<const float4*>(Wt + (size_t)(s * CIN + r) * COUT + q * 4);
            }
        }
        __syncthreads();
        // ---- compute: per k-quad, 4 W b128 + VT g b128 -> 16*VT FMA ----
        #pragma unroll
        for (int k4 = 0; k4 < CQ; ++k4) {
            const float4 w0 = *reinterpret_cast<const float4*>(&Wc[k4 * 4 + 0][qc * 4]);
            const float4 w1 = *reinterpret_cast<const float4*>(&Wc[k4 * 4 + 1][qc * 4]);
            const float4 w2 = *reinterpret_cast<const float4*>(&Wc[k4 * 4 + 2][qc * 4]);
            const float4 w3 = *reinterpret_cast<const float4*>(&Wc[k4 * 4 + 3][qc * 4]);
            #pragma unroll
            for (int i = 0; i < VT; ++i) {
                const float4 gv = *reinterpret_cast<const float4*>(&g[vg + i * VGN][k4 * 4]);
                acc[i].x += gv.x * w0.x + gv.y * w1.x + gv.z * w2.x + gv.w * w3.x;
                acc[i].y += gv.x * w0.y + gv.y * w1.y + gv.z * w2.y + gv.w * w3.y;
                acc[i].z += gv.x * w0.z + gv.y * w1.z + gv.z * w2.z + gv.w * w3.z;
                acc[i].w += gv.x * w0.w + gv.y * w1.w + gv.z * w2.w + gv.w * w3.w;
            }
        }
    }

    const float4 bv = *reinterpret_cast<const float4*>(bias + qc * 4);
    #pragma unroll
    for (int i = 0; i < VT; ++i) {
        float4 a = acc[i];
        a.x += bv.x; a.y += bv.y; a.z += bv.z; a.w += bv.w;
        if constexpr (ELU) {
            a.x = a.x > 0.f ? a.x : expm1f(a.x);
            a.y = a.y > 0.f ? a.y : expm1f(a.y);
            a.z = a.z > 0.f ? a.z : expm1f(a.z);
            a.w = a.w > 0.f ? a.w : expm1f(a.w);
        }
        *reinterpret_cast<float4*>(
            out + ((size_t)b * N + v0 + vg + i * VGN) * COUT + qc * 4) = a;
    }
}

// ---------------- first conv (CIN=3): old simple variant, tiny workload ----------------
template<int CIN, int COUT, int VPB, bool ELU>
__global__ __launch_bounds__(256) void conv_kernel(const float* __restrict__ x,
                                                   const int* __restrict__ idx,
                                                   const float* __restrict__ Wt,
                                                   const float* __restrict__ bias,
                                                   float* __restrict__ out,
                                                   int N) {
    constexpr int K   = CIN * 9;
    constexpr int GS  = K + 4;
    constexpr int TPV = COUT / 4;
    static_assert(VPB * TPV == 256, "block mapping");

    __shared__ float g[VPB][GS];
    __shared__ float Wc[K][COUT];
    __shared__ int   nbr[VPB][9];

    const int b  = blockIdx.y;
    const int v0 = blockIdx.x * VPB;
    const float* __restrict__ xb = x + (size_t)b * N * CIN;

    for (int t = threadIdx.x; t < VPB * 9; t += 256)
        nbr[t / 9][t % 9] = idx[v0 * 9 + t];
    __syncthreads();

    constexpr int EPV = 9 * CIN;
    for (int e = threadIdx.x; e < VPB * EPV; e += 256) {
        const int v = e / EPV, r = e - v * EPV;
        const int s = r / CIN, c = r - s * CIN;
        g[v][r] = xb[(size_t)nbr[v][s] * CIN + c];
    }
    for (int q = threadIdx.x; q < K * (COUT / 4); q += 256) {
        const int kk = q / (COUT / 4), cq = q - kk * (COUT / 4);
        *reinterpret_cast<float4*>(&Wc[kk][cq * 4]) =
            *reinterpret_cast<const float4*>(Wt + (size_t)kk * COUT + cq * 4);
    }
    __syncthreads();

    const int v  = threadIdx.x / TPV;
    const int cb = (threadIdx.x % TPV) * 4;
    float a0 = 0.f, a1 = 0.f, a2 = 0.f, a3 = 0.f;
    #pragma unroll 9
    for (int kk = 0; kk < K; ++kk) {
        const float  gv = g[v][kk];
        const float4 w  = *reinterpret_cast<const float4*>(&Wc[kk][cb]);
        a0 += gv * w.x; a1 += gv * w.y; a2 += gv * w.z; a3 += gv * w.w;
    }

    const float4 bv = *reinterpret_cast<const float4*>(bias + cb);
    a0 += bv.x; a1 += bv.y; a2 += bv.z; a3 += bv.w;
    if constexpr (ELU) {
        a0 = a0 > 0.f ? a0 : expm1f(a0);
        a1 = a1 > 0.f ? a1 : expm1f(a1);
        a2 = a2 > 0.f ? a2 : expm1f(a2);
        a3 = a3 > 0.f ? a3 : expm1f(a3);
    }
    float4 o; o.x = a0; o.y = a1; o.z = a2; o.w = a3;
    *reinterpret_cast<float4*>(out + ((size_t)b * N + v0 + v) * COUT + cb) = o;
}

// ---------------- final conv, COUT=3, CIN=32, no ELU ----------------
__global__ __launch_bounds__(256) void out_conv_kernel(const float* __restrict__ x,
                                                       const int* __restrict__ idx,
                                                       const float* __restrict__ Wt, // (288,3)
                                                       const float* __restrict__ bias,
                                                       float* __restrict__ out,
                                                       int N) {
    __shared__ float Wl[288 * 3];
    for (int t = threadIdx.x; t < 288 * 3; t += 256) Wl[t] = Wt[t];
    __syncthreads();
    const int b = blockIdx.y;
    const int v = blockIdx.x * 256 + threadIdx.x;
    const float* __restrict__ xb = x + (size_t)b * N * 32;
    float a0 = bias[0], a1 = bias[1], a2 = bias[2];
    #pragma unroll
    for (int s = 0; s < 9; ++s) {
        const int n = idx[v * 9 + s];
        const float* xs = xb + (size_t)n * 32;
        #pragma unroll
        for (int cq = 0; cq < 8; ++cq) {
            const float4 xv = *reinterpret_cast<const float4*>(xs + cq * 4);
            const int k = (s * 32 + cq * 4) * 3;
            a0 += xv.x * Wl[k + 0] + xv.y * Wl[k + 3] + xv.z * Wl[k + 6] + xv.w * Wl[k + 9];
            a1 += xv.x * Wl[k + 1] + xv.y * Wl[k + 4] + xv.z * Wl[k + 7] + xv.w * Wl[k + 10];
            a2 += xv.x * Wl[k + 2] + xv.y * Wl[k + 5] + xv.z * Wl[k + 8] + xv.w * Wl[k + 11];
        }
    }
    float* o = out + ((size_t)b * N + v) * 3;
    o[0] = a0; o[1] = a1; o[2] = a2;
}

// ---------------- pool: out[b,r,:] = sum_{j<3} val[3r+j] * x[b, col[3r+j], :] ----------------
template<int C>
__global__ __launch_bounds__(256) void pool_kernel(const float* __restrict__ x,
                                                   const int* __restrict__ col,
                                                   const float* __restrict__ val,
                                                   float* __restrict__ out,
                                                   int Nout, int Nin) {
    constexpr int CQ = C / 4;
    const int q = blockIdx.x * 256 + threadIdx.x;
    if (q >= BATCH * Nout * CQ) return;
    const int cq = q % CQ;
    const int r  = (q / CQ) % Nout;
    const int b  = q / (CQ * Nout);
    float ax = 0.f, ay = 0.f, az = 0.f, aw = 0.f;
    #pragma unroll
    for (int j = 0; j < 3; ++j) {
        const int   c0 = col[3 * r + j];
        const float vl = val[3 * r + j];
        const float4 xv = *reinterpret_cast<const float4*>(
            x + ((size_t)b * Nin + c0) * C + cq * 4);
        ax += vl * xv.x; ay += vl * xv.y; az += vl * xv.z; aw += vl * xv.w;
    }
    float4 o; o.x = ax; o.y = ay; o.z = az; o.w = aw;
    *reinterpret_cast<float4*>(out + ((size_t)b * Nout + r) * C + cq * 4) = o;
}

// ---------------- encoder FC: z = sigmoid(h @ fcW^T + fcb), h (16,8192) ----------------
__global__ __launch_bounds__(256) void fc_enc_kernel(const float* __restrict__ h,
                                                     const float* __restrict__ W,   // (256, 8192)
                                                     const float* __restrict__ bias,
                                                     float* __restrict__ z,
                                                     float* __restrict__ out_z,
                                                     float* __restrict__ out_mu) {
    const int l = blockIdx.x;                 // latent index
    const float* __restrict__ wr = W + (size_t)l * 8192;
    float acc[BATCH];
    #pragma unroll
    for (int b = 0; b < BATCH; ++b) acc[b] = 0.f;
    for (int k = threadIdx.x * 4; k < 8192; k += 256 * 4) {
        const float4 w4 = *reinterpret_cast<const float4*>(wr + k);
        #pragma unroll
        for (int b = 0; b < BATCH; ++b) {
            const float4 h4 = *reinterpret_cast<const float4*>(h + (size_t)b * 8192 + k);
            acc[b] += w4.x * h4.x + w4.y * h4.y + w4.z * h4.z + w4.w * h4.w;
        }
    }
    __shared__ float red[BATCH][4];
    const int wid = threadIdx.x >> 6, lane = threadIdx.x & 63;
    #pragma unroll
    for (int b = 0; b < BATCH; ++b) {
        float v = acc[b];
        for (int off = 32; off; off >>= 1) v += __shfl_down(v, off);
        if (lane == 0) red[b][wid] = v;
    }
    __syncthreads();
    if (threadIdx.x < BATCH) {
        const int b = threadIdx.x;
        float s = red[b][0] + red[b][1] + red[b][2] + red[b][3] + bias[l];
        s = 1.f / (1.f + expf(-s));
        z[b * 256 + l]      = s;
        out_z[b * 256 + l]  = s;
        out_mu[b * 256 + l] = s;
    }
}

// ---------------- decoder FC: h = z @ dfcW^T + dfcb -> (16, 8192) ----------------
__global__ __launch_bounds__(256) void fc_dec_kernel(const float* __restrict__ z,   // (16,256)
                                                     const float* __restrict__ W,   // (8192,256)
                                                     const float* __restrict__ bias,
                                                     float* __restrict__ out) {     // (16,8192)
    __shared__ float zl[BATCH * 256];
    for (int t = threadIdx.x; t < BATCH * 256; t += 256) zl[t] = z[t];
    __syncthreads();
    const int m = blockIdx.x * 256 + threadIdx.x;   // 8192 threads
    const float* __restrict__ wr = W + (size_t)m * 256;
    float acc[BATCH];
    #pragma unroll
    for (int b = 0; b < BATCH; ++b) acc[b] = 0.f;
    for (int l = 0; l < 256; l += 4) {
        const float4 w4 = *reinterpret_cast<const float4*>(wr + l);
        #pragma unroll
        for (int b = 0; b < BATCH; ++b) {
            acc[b] += w4.x * zl[b * 256 + l]     + w4.y * zl[b * 256 + l + 1]
                    + w4.z * zl[b * 256 + l + 2] + w4.w * zl[b * 256 + l + 3];
        }
    }
    const float bm = bias[m];
    #pragma unroll
    for (int b = 0; b < BATCH; ++b) out[(size_t)b * 8192 + m] = acc[b] + bm;
}

// ---------------- host-side orchestration ----------------
extern "C" void kernel_launch(void* const* d_in, const int* in_sizes, int n_in,
                              void* d_out, int out_size, void* d_ws, size_t ws_size,
                              hipStream_t stream) {
    (void)in_sizes; (void)n_in; (void)out_size; (void)ws_size;

    const float* x = (const float*)d_in[0];
    const int* si[4] = {(const int*)d_in[1], (const int*)d_in[2],
                        (const int*)d_in[3], (const int*)d_in[4]};
    const int*   dcol[4]; const float* dval[4];
    const int*   ucol[4]; const float* uval[4];
    for (int i = 0; i < 4; ++i) {
        dcol[i] = (const int*)  d_in[5 + 6 * i + 1];
        dval[i] = (const float*)d_in[5 + 6 * i + 2];
        ucol[i] = (const int*)  d_in[5 + 6 * i + 4];
        uval[i] = (const float*)d_in[5 + 6 * i + 5];
    }
    const float *enW[4], *enb[4], *deW[4], *deb[4];
    for (int i = 0; i < 4; ++i) {
        enW[i] = (const float*)d_in[29 + 2 * i];
        enb[i] = (const float*)d_in[30 + 2 * i];
        deW[i] = (const float*)d_in[41 + 2 * i];
        deb[i] = (const float*)d_in[42 + 2 * i];
    }
    const float* fcW  = (const float*)d_in[37];
    const float* fcb  = (const float*)d_in[38];
    const float* dfcW = (const float*)d_in[39];
    const float* dfcb = (const float*)d_in[40];
    const float* outW = (const float*)d_in[49];
    const float* outb = (const float*)d_in[50];

    // workspace layout (floats): A | Bb | z | transposed weights  (~135 MB total)
    float* ws = (float*)d_ws;
    float* A  = ws;
    float* Bb = A  + (size_t)BATCH * NN0 * 32;
    float* z  = Bb + (size_t)BATCH * NN0 * 32;
    float* wt_en0 = z + BATCH * 256;
    float* wt_en1 = wt_en0 + 27  * 32;
    float* wt_en2 = wt_en1 + 288 * 32;
    float* wt_en3 = wt_en2 + 288 * 32;
    float* wt_de0 = wt_en3 + 288 * 64;
    float* wt_de1 = wt_de0 + 576 * 64;
    float* wt_de2 = wt_de1 + 576 * 32;
    float* wt_de3 = wt_de2 + 288 * 32;
    float* wt_out = wt_de3 + 288 * 32;

    float* out   = (float*)d_out;                     // (16, 32768, 3)
    float* out_z = out + (size_t)BATCH * NN0 * 3;     // (16, 256)
    float* out_mu = out_z + BATCH * 256;              // (16, 256)

    auto T = [&](const float* W, float* Wt, int CO, int K) {
        int n = CO * K;
        transpose_w<<<(n + 255) / 256, 256, 0, stream>>>(W, Wt, CO, K);
    };
    T(enW[0], wt_en0, 32, 27);
    T(enW[1], wt_en1, 32, 288);
    T(enW[2], wt_en2, 32, 288);
    T(enW[3], wt_en3, 64, 288);
    T(deW[0], wt_de0, 64, 576);
    T(deW[1], wt_de1, 32, 576);
    T(deW[2], wt_de2, 32, 288);
    T(deW[3], wt_de3, 32, 288);
    T(outW,   wt_out, 3,  288);

    // ---------------- encoder ----------------
    conv_kernel<3, 32, 32, true><<<dim3(NN0 / 32, BATCH), 256, 0, stream>>>(
        x, si[0], wt_en0, enb[0], A, NN0);
    pool_kernel<32><<<(BATCH * NN1 * 8) / 256, 256, 0, stream>>>(A, dcol[0], dval[0], Bb, NN1, NN0);
    conv_tiled<32, 32, 128, true><<<dim3(NN1 / 128, BATCH), 256, 0, stream>>>(
        Bb, si[1], wt_en1, enb[1], A, NN1);
    pool_kernel<32><<<(BATCH * NN2 * 8) / 256, 256, 0, stream>>>(A, dcol[1], dval[1], Bb, NN2, NN1);
    conv_tiled<32, 32, 128, true><<<dim3(NN2 / 128, BATCH), 256, 0, stream>>>(
        Bb, si[2], wt_en2, enb[2], A, NN2);
    pool_kernel<32><<<(BATCH * NN3 * 8) / 256, 256, 0, stream>>>(A, dcol[2], dval[2], Bb, NN3, NN2);
    conv_tiled<32, 64, 32, true><<<dim3(NN3 / 32, BATCH), 256, 0, stream>>>(
        Bb, si[3], wt_en3, enb[3], A, NN3);
    pool_kernel<64><<<(BATCH * NN4 * 16) / 256, 256, 0, stream>>>(A, dcol[3], dval[3], Bb, NN4, NN3);

    // ---------------- latent ----------------
    fc_enc_kernel<<<256, 256, 0, stream>>>(Bb, fcW, fcb, z, out_z, out_mu);
    fc_dec_kernel<<<32, 256, 0, stream>>>(z, dfcW, dfcb, A);

    // ---------------- decoder ----------------
    pool_kernel<64><<<(BATCH * NN3 * 16) / 256, 256, 0, stream>>>(A, ucol[3], uval[3], Bb, NN3, NN4);
    conv_tiled<64, 64, 32, true><<<dim3(NN3 / 32, BATCH), 256, 0, stream>>>(
        Bb, si[3], wt_de0, deb[0], A, NN3);
    pool_kernel<64><<<(BATCH * NN2 * 16) / 256, 256, 0, stream>>>(A, ucol[2], uval[2], Bb, NN2, NN3);
    conv_tiled<64, 32, 64, true><<<dim3(NN2 / 64, BATCH), 256, 0, stream>>>(
        Bb, si[2], wt_de1, deb[1], A, NN2);
    pool_kernel<32><<<(BATCH * NN1 * 8) / 256, 256, 0, stream>>>(A, ucol[1], uval[1], Bb, NN1, NN2);
    conv_tiled<32, 32, 128, true><<<dim3(NN1 / 128, BATCH), 256, 0, stream>>>(
        Bb, si[1], wt_de2, deb[2], A, NN1);
    pool_kernel<32><<<(BATCH * NN0 * 8) / 256, 256, 0, stream>>>(A, ucol[0], uval[0], Bb, NN0, NN1);
    conv_tiled<32, 32, 128, true><<<dim3(NN0 / 128, BATCH), 256, 0, stream>>>(
        Bb, si[0], wt_de3, deb[3], A, NN0);

    // ---------------- output head ----------------
    out_conv_kernel<<<dim3(NN0 / 256, BATCH), 256, 0, stream>>>(
        A, si[0], wt_out, outb, out, NN0);
}